// Round 14
// baseline (10711.808 us; speedup 1.0000x reference)
//
#include <hip/hip_runtime.h>
#include <hip/hip_bf16.h>
#include <stdint.h>

// GRU fused scan: B=128, T=512, I=H=512.
// CHAIN-INTERLEAVED build on the r6-proven protocol (3553us):
// 128 wgs x 192 threads (3 waves = gates r,z,n). wg w owns hidden units
// [ (w>>2)*16, +16 ) for TWO independent batch-groups:
//   chain A: bgrp = w&3     (batch rows [ (w&3)*16, +16))
//   chain B: bgrp = 4+(w&3) (batch rows [ (4+(w&3))*16, +16))
// Same weights/biases serve both chains (weights depend only on unit slice).
// Per t: full r6 step for A, then full r6 step for B. A's publish->flag->
// poll round trip overlaps B's compute and vice versa (latency hiding by
// independent-chain interleave; period -> max(L, ...) not L+C).
// Protocol per chain = r6 byte-for-byte: agent-scope relaxed atomics for h
// (bf16, double-buffered), monotonic flag[bgrp*32+ugrp]=t+1 stored after
// s_waitcnt vmcnt(0) drain, 64-lane ballot poll of 32 flags. Integer RNE
// bf16 cvt ONLY (asm cvt_pk is a proven -42% poison, r11/m240).
// ws: 256KB hbuf + 1KB flags (r6-proven footprint).

static constexpr int INPUT = 512;
static constexpr int HID   = 512;
static constexpr int NB    = 128;
static constexpr int TLEN  = 512;
static constexpr int BGRPS = 8;
static constexpr int UGRPS = 32;

typedef __attribute__((ext_vector_type(4))) float f32x4;
typedef __attribute__((ext_vector_type(8))) short s16x8;

static __device__ __forceinline__ unsigned short f2bf(float f) {
  unsigned u = __builtin_bit_cast(unsigned, f);
  u += 0x7FFFu + ((u >> 16) & 1u);   // RNE
  return (unsigned short)(u >> 16);
}

// 8 consecutive fp32 -> bf16x8 (integer RNE; r6-proven, no asm)
static __device__ __forceinline__ s16x8 cvt8(const float* p) {
  f32x4 a = *(const f32x4*)p;
  f32x4 b = *(const f32x4*)(p + 4);
  s16x8 r;
  r[0] = (short)f2bf(a[0]); r[1] = (short)f2bf(a[1]);
  r[2] = (short)f2bf(a[2]); r[3] = (short)f2bf(a[3]);
  r[4] = (short)f2bf(b[0]); r[5] = (short)f2bf(b[1]);
  r[6] = (short)f2bf(b[2]); r[7] = (short)f2bf(b[3]);
  return r;
}

// One full r6 step for one chain. Returns with acc_a holding the x-GEMM for
// step t+1 (issued after publish so HBM/flag latency hides under it).
static __device__ __forceinline__ void gru_step(
    int t, int bgrp, int ugrp, int b0, int u0,
    int g, int lane, int ln, int kg, int tid,
    const s16x8* wa, const s16x8* wb, float bv, float bn,
    const float* xrow, int hoff,
    unsigned short* __restrict__ hbuf, unsigned int* __restrict__ flags,
    float* __restrict__ out, float (*xch)[4][16][16],
    float* hold, f32x4& acc_a)
{
  // ---- wait: all 32 wgs of this bgrp have published h[t] (flag >= t) ----
  if (t > 0) {
    const unsigned* fp = &flags[bgrp * UGRPS + (lane & 31)];
    unsigned fv;
    do {
      fv = __hip_atomic_load(fp, __ATOMIC_RELAXED, __HIP_MEMORY_SCOPE_AGENT);
    } while (~__ballot(fv >= (unsigned)t));
    __builtin_amdgcn_sched_barrier(0);   // no hoist of h loads above the wait
  }

  // ---- load h[t] fragments (agent-scope relaxed; r6-proven) ----
  const unsigned long long* hb =
      (const unsigned long long*)(hbuf + (size_t)(t & 1) * (NB * HID) + hoff);
  unsigned long long q0[16], q1[16];
#pragma unroll
  for (int ks = 0; ks < 16; ++ks) {
    q0[ks] = __hip_atomic_load(hb + ks * 8,     __ATOMIC_RELAXED, __HIP_MEMORY_SCOPE_AGENT);
    q1[ks] = __hip_atomic_load(hb + ks * 8 + 1, __ATOMIC_RELAXED, __HIP_MEMORY_SCOPE_AGENT);
  }

  // ---- recurrent GEMM: hg = h[t] @ Whh^T ----
  f32x4 acc_b0 = {0.f, 0.f, 0.f, 0.f}, acc_b1 = {0.f, 0.f, 0.f, 0.f};
#pragma unroll
  for (int ks = 0; ks < 16; ks += 2) {
    union { unsigned long long q[2]; s16x8 s; } ua, ub;
    ua.q[0] = q0[ks];     ua.q[1] = q1[ks];
    ub.q[0] = q0[ks + 1]; ub.q[1] = q1[ks + 1];
    acc_b0 = __builtin_amdgcn_mfma_f32_16x16x32_bf16(ua.s, wb[ks],     acc_b0, 0, 0, 0);
    acc_b1 = __builtin_amdgcn_mfma_f32_16x16x32_bf16(ub.s, wb[ks + 1], acc_b1, 0, 0, 0);
  }
  f32x4 acc_b = acc_b0 + acc_b1;

  // ---- exchange gate pre-activations across the 3 waves (dbuf LDS) ----
  float (*xc)[16][16] = xch[t & 1];
  if (g == 0)      { f32x4 s = acc_a + acc_b; *(f32x4*)&xc[0][ln][kg * 4] = s; }
  else if (g == 1) { f32x4 s = acc_a + acc_b; *(f32x4*)&xc[1][ln][kg * 4] = s; }
  else             { *(f32x4*)&xc[2][ln][kg * 4] = acc_a;
                     *(f32x4*)&xc[3][ln][kg * 4] = acc_b; }
  __syncthreads();
  f32x4 Sr  = *(const f32x4*)&xc[0][ln][kg * 4];
  f32x4 Sz  = *(const f32x4*)&xc[1][ln][kg * 4];
  f32x4 Snx = *(const f32x4*)&xc[2][ln][kg * 4];
  f32x4 Snh = *(const f32x4*)&xc[3][ln][kg * 4];

  // ---- gate math (all waves redundantly; keeps h_old in regs everywhere) ----
  float hnew[4];
#pragma unroll
  for (int i = 0; i < 4; ++i) {
    float r = 1.f / (1.f + __expf(-Sr[i]));
    float z = 1.f / (1.f + __expf(-Sz[i]));
    float pre = Snx[i] + r * (Snh[i] + bn);
    float e = __expf(2.f * pre);
    float n = 1.f - 2.f / (e + 1.f);   // tanh, overflow-safe
    hnew[i] = n + z * (hold[i] - n);
    hold[i] = hnew[i];
  }

  if (t == TLEN - 1) {
    if (g == 0) {
#pragma unroll
      for (int i = 0; i < 4; ++i)
        out[(size_t)(b0 + kg * 4 + i) * HID + u0 + ln] = hnew[i];
    }
  } else {
    // ---- publish h[t+1], drain, set flag = t+1 (r6-proven) ----
    if (g == 0) {
      unsigned short* hbn = hbuf + (size_t)((t + 1) & 1) * (NB * HID);
#pragma unroll
      for (int i = 0; i < 4; ++i) {
        int v  = (int)f2bf(hnew[i]);
        int o1 = __shfl_xor(v, 1);
        unsigned int p = (unsigned int)(v & 0xffff) | ((unsigned int)(o1 & 0xffff) << 16);
        unsigned int o2 = (unsigned int)__shfl_xor((int)p, 2);
        if ((ln & 3) == 0) {
          unsigned long long q = (unsigned long long)p | ((unsigned long long)o2 << 32);
          __hip_atomic_store(
              (unsigned long long*)(hbn + (size_t)(b0 + kg * 4 + i) * HID + u0 + ln),
              q, __ATOMIC_RELAXED, __HIP_MEMORY_SCOPE_AGENT);
        }
      }
      asm volatile("s_waitcnt vmcnt(0)" ::: "memory");  // h stores at IF
      if (tid == 0)
        __hip_atomic_store(&flags[bgrp * UGRPS + ugrp], (unsigned)(t + 1),
                           __ATOMIC_RELAXED, __HIP_MEMORY_SCOPE_AGENT);
    }

    // ---- input-side GEMM for step t+1 (hides flag/data propagation) ----
    acc_a = (f32x4){bv, bv, bv, bv};
    const float* xp = xrow + (size_t)(t + 1) * INPUT;
#pragma unroll
    for (int ks = 0; ks < 16; ++ks) {
      s16x8 xa = cvt8(xp + ks * 32);
      acc_a = __builtin_amdgcn_mfma_f32_16x16x32_bf16(xa, wa[ks], acc_a, 0, 0, 0);
    }
  }
}

__global__ __launch_bounds__(192, 2) void gru_fused(
    const float* __restrict__ xs, const float* __restrict__ wih,
    const float* __restrict__ whh, const float* __restrict__ bias,
    const float* __restrict__ bias_n, float* __restrict__ out,
    unsigned short* __restrict__ hbuf, unsigned int* __restrict__ flags)
{
  const int w    = blockIdx.x;     // 0..127
  const int bgA  = w & 3;          // chain A batch-group (0..3)
  const int bgB  = 4 + (w & 3);    // chain B batch-group (4..7)
  const int ugrp = w >> 2;         // unit-slice 0..31 (same for both chains)
  const int b0A  = bgA * 16;
  const int b0B  = bgB * 16;
  const int u0   = ugrp * 16;
  const int tid  = threadIdx.x;
  const int g    = tid >> 6;       // 0=r, 1=z, 2=n
  const int lane = tid & 63;
  const int ln   = lane & 15;
  const int kg   = lane >> 4;

  __shared__ float xchA[2][4][16][16];   // 8 KB per chain (dbuf)
  __shared__ float xchB[2][4][16][16];

  // ---- preload weight fragments (shared by both chains) ----
  const int rowW = g * HID + u0 + ln;
  s16x8 wa[16], wb[16];
#pragma unroll
  for (int ks = 0; ks < 16; ++ks) {
    const int k = ks * 32 + kg * 8;
    wa[ks] = cvt8(wih + (size_t)rowW * INPUT + k);
    wb[ks] = cvt8(whh + (size_t)rowW * HID + k);
  }
  const float bv = bias[rowW];
  const float bn = bias_n[u0 + ln];

  const float* xrowA = xs + (size_t)(b0A + ln) * TLEN * INPUT + kg * 8;
  const float* xrowB = xs + (size_t)(b0B + ln) * TLEN * INPUT + kg * 8;
  const int hoffA = (b0A + ln) * HID + kg * 8;
  const int hoffB = (b0B + ln) * HID + kg * 8;

  float holdA[4] = {0.f, 0.f, 0.f, 0.f};
  float holdB[4] = {0.f, 0.f, 0.f, 0.f};

  // ---- prologue: x-GEMM t=0 for both chains ----
  f32x4 accA = {bv, bv, bv, bv}, accB = {bv, bv, bv, bv};
#pragma unroll
  for (int ks = 0; ks < 16; ++ks) {
    s16x8 xa = cvt8(xrowA + ks * 32);
    accA = __builtin_amdgcn_mfma_f32_16x16x32_bf16(xa, wa[ks], accA, 0, 0, 0);
  }
#pragma unroll
  for (int ks = 0; ks < 16; ++ks) {
    s16x8 xb = cvt8(xrowB + ks * 32);
    accB = __builtin_amdgcn_mfma_f32_16x16x32_bf16(xb, wa[ks], accB, 0, 0, 0);
  }

  for (int t = 0; t < TLEN; ++t) {
    // chain A step t (its publish latency hides under B's step + x-GEMMs)
    gru_step(t, bgA, ugrp, b0A, u0, g, lane, ln, kg, tid,
             wa, wb, bv, bn, xrowA, hoffA, hbuf, flags, out, xchA, holdA, accA);
    // chain B step t
    gru_step(t, bgB, ugrp, b0B, u0, g, lane, ln, kg, tid,
             wa, wb, bv, bn, xrowB, hoffB, hbuf, flags, out, xchB, holdB, accB);
  }
}

extern "C" void kernel_launch(void* const* d_in, const int* in_sizes, int n_in,
                              void* d_out, int out_size, void* d_ws, size_t ws_size,
                              hipStream_t stream) {
  const float* xs     = (const float*)d_in[0];
  const float* wih    = (const float*)d_in[1];
  const float* whh    = (const float*)d_in[2];
  const float* bias   = (const float*)d_in[3];
  const float* bias_n = (const float*)d_in[4];
  float* out = (float*)d_out;

  const size_t hbuf_bytes = (size_t)2 * NB * HID * sizeof(unsigned short); // 256 KB
  const size_t flg_bytes  = (size_t)BGRPS * UGRPS * sizeof(unsigned int);  // 1 KB
  unsigned short* hbuf  = (unsigned short*)d_ws;
  unsigned int*   flags = (unsigned int*)((char*)d_ws + hbuf_bytes);

  hipMemsetAsync(d_ws, 0, hbuf_bytes + flg_bytes, stream);

  gru_fused<<<dim3(128), dim3(192), 0, stream>>>(
      xs, wih, whh, bias, bias_n, out, hbuf, flags);
}

// Round 15
// 6273.489 us; speedup vs baseline: 1.7075x; 1.7075x over previous
//
#include <hip/hip_runtime.h>
#include <hip/hip_bf16.h>
#include <stdint.h>

// GRU fused scan: B=128, T=512, I=H=512.
// FAN-IN-16 build on the r6-proven protocol (3553us baseline):
// 128 wgs x 384 threads (6 waves). wave w: g = w%3 (gate r/z/n),
// uh = w/3 (unit-half). wg (bgrp = id&7, ugrp = id>>3) owns batch rows
// [bgrp*16,+16) and hidden units [ugrp*32 + uh*16, +16) per wave.
// Each wave does EXACTLY one r6-wave's work (16 units x 16 batch, 16+16
// MFMAs); per-wave serial work unchanged; only the rendezvous changes:
//   - 16 producers per bgrp (was 32), 16 flags polled (was 32)
//   - one flag per wg, stored by tid0 after a post-drain __syncthreads
//     (both publisher waves' vmcnt(0) precede the barrier -> h-before-flag
//     ordering preserved)
// bgrp = wg&7 maps 1:1 to XCDs under round-robin dispatch -> same-XCD xs
// L2 locality for free (no protocol change, pure placement effect).
// Everything else r6-verbatim: agent-scope relaxed atomics for h (bf16,
// ring-2 in d_ws), monotonic flag=t+1, integer RNE cvt ONLY (asm cvt_pk
// is a proven -42% poison), x-GEMM for t+1 after publish (hides flag hop).
// ws: 256KB hbuf + 512B flags. launch_bounds(384,1): no VGPR cap (r13's
// spill trap), 1 wg/CU is all we need (128 wgs on 256 CUs).

static constexpr int INPUT = 512;
static constexpr int HID   = 512;
static constexpr int NB    = 128;
static constexpr int TLEN  = 512;
static constexpr int BGRPS = 8;
static constexpr int UGRPS = 16;   // wgs per bgrp (fan-in)

typedef __attribute__((ext_vector_type(4))) float f32x4;
typedef __attribute__((ext_vector_type(8))) short s16x8;

static __device__ __forceinline__ unsigned short f2bf(float f) {
  unsigned u = __builtin_bit_cast(unsigned, f);
  u += 0x7FFFu + ((u >> 16) & 1u);   // RNE
  return (unsigned short)(u >> 16);
}

// 8 consecutive fp32 -> bf16x8 (integer RNE; r6-proven, no asm)
static __device__ __forceinline__ s16x8 cvt8(const float* p) {
  f32x4 a = *(const f32x4*)p;
  f32x4 b = *(const f32x4*)(p + 4);
  s16x8 r;
  r[0] = (short)f2bf(a[0]); r[1] = (short)f2bf(a[1]);
  r[2] = (short)f2bf(a[2]); r[3] = (short)f2bf(a[3]);
  r[4] = (short)f2bf(b[0]); r[5] = (short)f2bf(b[1]);
  r[6] = (short)f2bf(b[2]); r[7] = (short)f2bf(b[3]);
  return r;
}

__global__ __launch_bounds__(384, 1) void gru_fused(
    const float* __restrict__ xs, const float* __restrict__ wih,
    const float* __restrict__ whh, const float* __restrict__ bias,
    const float* __restrict__ bias_n, float* __restrict__ out,
    unsigned short* __restrict__ hbuf, unsigned int* __restrict__ flags)
{
  const int wg   = blockIdx.x;
  const int bgrp = wg & 7;         // 1:1 with XCD under round-robin
  const int ugrp = wg >> 3;        // 0..15
  const int b0   = bgrp * 16;
  const int tid  = threadIdx.x;
  const int wv   = tid >> 6;       // 0..5
  const int g    = wv % 3;         // 0=r, 1=z, 2=n
  const int uh   = wv / 3;         // unit-half 0/1
  const int u0   = ugrp * 32 + uh * 16;
  const int lane = tid & 63;
  const int ln   = lane & 15;      // unit / batch-row index within tile
  const int kg   = lane >> 4;      // k-octet group 0..3

  __shared__ float xch[2][2][4][16][16];   // [dbuf][uh][slot][unit][batch]

  // ---- preload weight fragments into registers (one-time) ----
  const int rowW = g * HID + u0 + ln;      // row of [1536][512] weight matrices
  s16x8 wa[16], wb[16];
#pragma unroll
  for (int ks = 0; ks < 16; ++ks) {
    const int k = ks * 32 + kg * 8;
    wa[ks] = cvt8(wih + (size_t)rowW * INPUT + k);
    wb[ks] = cvt8(whh + (size_t)rowW * HID + k);
  }
  const float bv = bias[rowW];
  const float bn = bias_n[u0 + ln];

  const float* xrow = xs + (size_t)(b0 + ln) * TLEN * INPUT + kg * 8;
  const int hoff = (b0 + ln) * HID + kg * 8;   // ushort offset in one h slot

  float hold[4] = {0.f, 0.f, 0.f, 0.f};

  // ---- prologue: input-side GEMM for t = 0 ----
  f32x4 acc_a = {bv, bv, bv, bv};
#pragma unroll
  for (int ks = 0; ks < 16; ++ks) {
    s16x8 xa = cvt8(xrow + ks * 32);
    acc_a = __builtin_amdgcn_mfma_f32_16x16x32_bf16(xa, wa[ks], acc_a, 0, 0, 0);
  }

  for (int t = 0; t < TLEN; ++t) {
    // ---- wait: all 16 wgs of my bgrp have published h[t] (flag >= t) ----
    if (t > 0) {
      const unsigned* fp = &flags[bgrp * UGRPS + (lane & 15)];
      unsigned fv;
      do {
        fv = __hip_atomic_load(fp, __ATOMIC_RELAXED, __HIP_MEMORY_SCOPE_AGENT);
      } while (~__ballot(fv >= (unsigned)t));
      __builtin_amdgcn_sched_barrier(0);   // no hoist of h loads above the wait
    }

    // ---- load h[t] fragments (agent-scope relaxed; r6-proven) ----
    const unsigned long long* hb =
        (const unsigned long long*)(hbuf + (size_t)(t & 1) * (NB * HID) + hoff);
    unsigned long long q0[16], q1[16];
#pragma unroll
    for (int ks = 0; ks < 16; ++ks) {
      q0[ks] = __hip_atomic_load(hb + ks * 8,     __ATOMIC_RELAXED, __HIP_MEMORY_SCOPE_AGENT);
      q1[ks] = __hip_atomic_load(hb + ks * 8 + 1, __ATOMIC_RELAXED, __HIP_MEMORY_SCOPE_AGENT);
    }

    // ---- recurrent GEMM: hg = h[t] @ Whh^T ----
    f32x4 acc_b0 = {0.f, 0.f, 0.f, 0.f}, acc_b1 = {0.f, 0.f, 0.f, 0.f};
#pragma unroll
    for (int ks = 0; ks < 16; ks += 2) {
      union { unsigned long long q[2]; s16x8 s; } ua, ub;
      ua.q[0] = q0[ks];     ua.q[1] = q1[ks];
      ub.q[0] = q0[ks + 1]; ub.q[1] = q1[ks + 1];
      acc_b0 = __builtin_amdgcn_mfma_f32_16x16x32_bf16(ua.s, wb[ks],     acc_b0, 0, 0, 0);
      acc_b1 = __builtin_amdgcn_mfma_f32_16x16x32_bf16(ub.s, wb[ks + 1], acc_b1, 0, 0, 0);
    }
    f32x4 acc_b = acc_b0 + acc_b1;

    // ---- exchange gate pre-activations across the 3 gate-waves (per uh) ----
    float (*xc)[16][16] = xch[t & 1][uh];
    if (g == 0)      { f32x4 s = acc_a + acc_b; *(f32x4*)&xc[0][ln][kg * 4] = s; }
    else if (g == 1) { f32x4 s = acc_a + acc_b; *(f32x4*)&xc[1][ln][kg * 4] = s; }
    else             { *(f32x4*)&xc[2][ln][kg * 4] = acc_a;
                       *(f32x4*)&xc[3][ln][kg * 4] = acc_b; }
    __syncthreads();
    f32x4 Sr  = *(const f32x4*)&xc[0][ln][kg * 4];
    f32x4 Sz  = *(const f32x4*)&xc[1][ln][kg * 4];
    f32x4 Snx = *(const f32x4*)&xc[2][ln][kg * 4];
    f32x4 Snh = *(const f32x4*)&xc[3][ln][kg * 4];

    // ---- gate math (all waves redundantly; keeps h_old in regs everywhere) ----
    float hnew[4];
#pragma unroll
    for (int i = 0; i < 4; ++i) {
      float r = 1.f / (1.f + __expf(-Sr[i]));
      float z = 1.f / (1.f + __expf(-Sz[i]));
      float pre = Snx[i] + r * (Snh[i] + bn);
      float e = __expf(2.f * pre);
      float n = 1.f - 2.f / (e + 1.f);   // tanh, overflow-safe
      hnew[i] = n + z * (hold[i] - n);
      hold[i] = hnew[i];
    }

    if (t == TLEN - 1) {
      if (g == 0) {
#pragma unroll
        for (int i = 0; i < 4; ++i)
          out[(size_t)(b0 + kg * 4 + i) * HID + u0 + ln] = hnew[i];
      }
    } else {
      // ---- publish h[t+1] (both uh halves in parallel), per-wave drain ----
      if (g == 0) {
        unsigned short* hbn = hbuf + (size_t)((t + 1) & 1) * (NB * HID);
#pragma unroll
        for (int i = 0; i < 4; ++i) {
          int v  = (int)f2bf(hnew[i]);
          int o1 = __shfl_xor(v, 1);
          unsigned int p = (unsigned int)(v & 0xffff) | ((unsigned int)(o1 & 0xffff) << 16);
          unsigned int o2 = (unsigned int)__shfl_xor((int)p, 2);
          if ((ln & 3) == 0) {
            unsigned long long q = (unsigned long long)p | ((unsigned long long)o2 << 32);
            __hip_atomic_store(
                (unsigned long long*)(hbn + (size_t)(b0 + kg * 4 + i) * HID + u0 + ln),
                q, __ATOMIC_RELAXED, __HIP_MEMORY_SCOPE_AGENT);
          }
        }
        asm volatile("s_waitcnt vmcnt(0)" ::: "memory");  // my h stores at IF
      }
      __syncthreads();   // both publisher waves drained before the flag
      if (tid == 0)
        __hip_atomic_store(&flags[bgrp * UGRPS + ugrp], (unsigned)(t + 1),
                           __ATOMIC_RELAXED, __HIP_MEMORY_SCOPE_AGENT);

      // ---- input-side GEMM for step t+1 (hides flag/data propagation) ----
      acc_a = (f32x4){bv, bv, bv, bv};
      const float* xp = xrow + (size_t)(t + 1) * INPUT;
#pragma unroll
      for (int ks = 0; ks < 16; ++ks) {
        s16x8 xa = cvt8(xp + ks * 32);
        acc_a = __builtin_amdgcn_mfma_f32_16x16x32_bf16(xa, wa[ks], acc_a, 0, 0, 0);
      }
    }
  }
}

extern "C" void kernel_launch(void* const* d_in, const int* in_sizes, int n_in,
                              void* d_out, int out_size, void* d_ws, size_t ws_size,
                              hipStream_t stream) {
  const float* xs     = (const float*)d_in[0];
  const float* wih    = (const float*)d_in[1];
  const float* whh    = (const float*)d_in[2];
  const float* bias   = (const float*)d_in[3];
  const float* bias_n = (const float*)d_in[4];
  float* out = (float*)d_out;

  const size_t hbuf_bytes = (size_t)2 * NB * HID * sizeof(unsigned short); // 256 KB
  const size_t flg_bytes  = (size_t)BGRPS * UGRPS * sizeof(unsigned int);  // 512 B
  unsigned short* hbuf  = (unsigned short*)d_ws;
  unsigned int*   flags = (unsigned int*)((char*)d_ws + hbuf_bytes);

  hipMemsetAsync(d_ws, 0, hbuf_bytes + flg_bytes, stream);

  gru_fused<<<dim3(BGRPS * UGRPS), dim3(384), 0, stream>>>(
      xs, wih, whh, bias, bias_n, out, hbuf, flags);
}